// Round 1
// baseline (288.039 us; speedup 1.0000x reference)
//
#include <hip/hip_runtime.h>

// R6: fixed-field decomposition. Each block owns ONE field d (blockIdx.x & 15)
// and a 256-point chunk (blockIdx.x >> 4). All weights/biases for field d are
// loaded ONCE into per-lane registers in frag layout — no LDS, no
// __syncthreads, no d-loop. The stream loop per wave is 4 independent
// {x-load -> MFMA x3 -> store} tile chains, fully unrollable/pipelinable.
//
// Legacy mfma_f32_16x16x16f16 shape (known-good from R5): B-frag
// (k = 4*quad + j) matches C/D-frag (row = 4*quad + i) quad-for-quad, so
// layer chaining is 4 fmax + 2 cvt_pkrtz per transition, no cross-lane ops.
//
// Frag layouts (16x16x16, CDNA family):
//   A[m][k]: lane m=lane&15, k = 4*(lane>>4) + j   (4 f16, 2 VGPRs)
//   B[k][n]: lane n=lane&15, k = 4*(lane>>4) + j
//   C/D:     lane n=lane&15, row = 4*(lane>>4) + i (4 fp32)
// L1: K=3 pads inside quad 0; B-quads>=1 are true zeros so A-quads>=1
// (broadcast of the same 4 halfs) are harmless. L3: only rows 0..2 (quad 0)
// are stored, so A3 rows >=3 are zeroed only to avoid OOB weight reads.
// Bias rides in the MFMA C operand (fp32, exact). Numerics identical to R5.

#define MFMA16(a, b, c) __builtin_amdgcn_mfma_f32_16x16x16f16((a), (b), (c), 0, 0, 0)

#define TILES_PER_WAVE 4
#define WAVES_PER_BLOCK 4
#define PTS_PER_BLOCK (TILES_PER_WAVE * WAVES_PER_BLOCK * 16)  // 256

typedef __fp16 pk16x2 __attribute__((ext_vector_type(2)));   // cvt_pkrtz return type
typedef _Float16 half4_t __attribute__((ext_vector_type(4)));
typedef float float4_t __attribute__((ext_vector_type(4)));

union H2I { pk16x2 h; int i; };
union Frag { half4_t v; int i[2]; };

__device__ __forceinline__ int pkrtz(float a, float b) {
    H2I u; u.h = __builtin_amdgcn_cvt_pkrtz(a, b); return u.i;
}

__global__ __launch_bounds__(256) void fields_fixedd_kernel(
    const float* __restrict__ x,
    const float* __restrict__ W1, const float* __restrict__ b1,
    const float* __restrict__ W2, const float* __restrict__ b2,
    const float* __restrict__ W3, const float* __restrict__ b3,
    float* __restrict__ out, int N)
{
    const int lane = threadIdx.x & 63;
    const int wave = threadIdx.x >> 6;
    const int q    = lane >> 4;        // quad 0..3
    const int n16  = lane & 15;        // column (point) within tile / row m for A

    const int d     = blockIdx.x & 15;         // 16 consecutive blocks share an x-chunk
    const int chunk = blockIdx.x >> 4;
    const int base  = chunk * PTS_PER_BLOCK + wave * (TILES_PER_WAVE * 16);

    // ---- weights -> registers, frag-ready (once per block) ----
    Frag a1, a2, a3;
    {
        const float* w1 = W1 + (d * 16 + n16) * 3;
        a1.v = (half4_t){(_Float16)w1[0], (_Float16)w1[1], (_Float16)w1[2],
                         (_Float16)0.f};
        const float4_t w2 = *(const float4_t*)(W2 + (d * 16 + n16) * 16 + q * 4);
        a2.v = (half4_t){(_Float16)w2.x, (_Float16)w2.y, (_Float16)w2.z,
                         (_Float16)w2.w};
        if (n16 < 3) {
            const float4_t w3 = *(const float4_t*)(W3 + (d * 3 + n16) * 16 + q * 4);
            a3.v = (half4_t){(_Float16)w3.x, (_Float16)w3.y, (_Float16)w3.z,
                             (_Float16)w3.w};
        } else {
            a3.i[0] = 0; a3.i[1] = 0;
        }
    }
    const float4_t bias1 = *(const float4_t*)(b1 + d * 16 + q * 4);
    const float4_t bias2 = *(const float4_t*)(b2 + d * 16 + q * 4);
    float4_t bias3 = (float4_t){0.f, 0.f, 0.f, 0.f};
    if (q == 0) {
        bias3.x = b3[d * 3 + 0];
        bias3.y = b3[d * 3 + 1];
        bias3.z = b3[d * 3 + 2];
    }

    // ---- x B-frags: quad 0 holds k=0..3 = {x0,x1,x2,0}; quads 1..3 zero ----
    Frag xf[TILES_PER_WAVE];
#pragma unroll
    for (int t = 0; t < TILES_PER_WAVE; ++t) {
        const int pt = base + t * 16 + n16;
        float x0 = 0.f, x1 = 0.f, x2 = 0.f;
        if (q == 0 && pt < N) {
            x0 = x[pt];
            x1 = x[(size_t)N + pt];
            x2 = x[2 * (size_t)N + pt];
        }
        xf[t].i[0] = pkrtz(x0, x1);
        xf[t].i[1] = pkrtz(x2, 0.f);
    }

    float* o0 = out + (size_t)(d * 3 + 0) * N;
    float* o1 = out + (size_t)(d * 3 + 1) * N;
    float* o2 = out + (size_t)(d * 3 + 2) * N;

#pragma unroll
    for (int t = 0; t < TILES_PER_WAVE; ++t) {
        // Layer 1: h1 = relu(W1 x + b1)   (D-layout == next B-layout)
        float4_t acc = MFMA16(a1.v, xf[t].v, bias1);
        Frag bf;
        bf.i[0] = pkrtz(fmaxf(acc.x, 0.f), fmaxf(acc.y, 0.f));
        bf.i[1] = pkrtz(fmaxf(acc.z, 0.f), fmaxf(acc.w, 0.f));
        // Layer 2
        acc = MFMA16(a2.v, bf.v, bias2);
        Frag cf;
        cf.i[0] = pkrtz(fmaxf(acc.x, 0.f), fmaxf(acc.y, 0.f));
        cf.i[1] = pkrtz(fmaxf(acc.z, 0.f), fmaxf(acc.w, 0.f));
        // Layer 3 (no relu); quad 0 rows 0..2 are outputs o=0,1,2 of point n16
        acc = MFMA16(a3.v, cf.v, bias3);
        const int pt = base + t * 16 + n16;
        if (q == 0 && pt < N) {
            o0[pt] = acc.x;
            o1[pt] = acc.y;
            o2[pt] = acc.z;
        }
    }
}

extern "C" void kernel_launch(void* const* d_in, const int* in_sizes, int n_in,
                              void* d_out, int out_size, void* d_ws, size_t ws_size,
                              hipStream_t stream) {
    const float* x  = (const float*)d_in[0];
    const float* W1 = (const float*)d_in[1];
    const float* b1 = (const float*)d_in[2];
    const float* W2 = (const float*)d_in[3];
    const float* b2 = (const float*)d_in[4];
    const float* W3 = (const float*)d_in[5];
    const float* b3 = (const float*)d_in[6];
    float* out = (float*)d_out;

    const int N = in_sizes[0] / 3;  // x is [1,3,N]
    const int chunks = (N + PTS_PER_BLOCK - 1) / PTS_PER_BLOCK;
    const int grid = chunks * 16;   // 16 fields interleaved in the low bits
    fields_fixedd_kernel<<<grid, 256, 0, stream>>>(x, W1, b1, W2, b2, W3, b3, out, N);
}